// Round 3
// 4471.836 us; speedup vs baseline: 1.2560x; 1.2560x over previous
//
#include <hip/hip_runtime.h>

// GhostGRU persistent-RNN kernel for MI355X (gfx950), round 5.
// Rounds 3/4 (XCD-L2 inline-asm experiments) failed without profiles; this
// round reverts to the PROVEN round-2 base (builtin atomics only, no inline
// asm anywhere) and applies only safe data-flow improvements:
//  - newh half of h persists in LDS across steps (loop top stages ghost only);
//  - rstate staged by idle waves 0/1 while cand wave prefetches u and runs
//    its 24 x+ghost MFMAs (hides the rstate LLC round trip);
//  - x_t prefetched into registers one step ahead (HBM latency off the
//    loop-top critical path);
//  - all staging loads are 8-byte relaxed agent atomics (half the VMEM ops);
//  - group barrier splits the RMW counter line from the polled go-word line
//    (32 RMWs on a line nobody polls; pollers read a 1-writer line).

typedef unsigned short ushort_t;
typedef unsigned long long ull_t;
typedef __attribute__((ext_vector_type(8))) short short8;   // 8 x bf16 (4 VGPRs)
typedef __attribute__((ext_vector_type(4))) float f32x4;

#define NB 128
#define NT 512
#define NF 256
#define NH 1024
#define KGATE 1280

#define AT_LOAD(p)     __hip_atomic_load((p), __ATOMIC_RELAXED, __HIP_MEMORY_SCOPE_AGENT)
#define AT_STORE(p,v)  __hip_atomic_store((p), (v), __ATOMIC_RELAXED, __HIP_MEMORY_SCOPE_AGENT)

__device__ __forceinline__ float bf2f(ushort_t u) {
  union { unsigned int i; float f; } v; v.i = ((unsigned int)u) << 16; return v.f;
}
__device__ __forceinline__ ushort_t f2bf(float f) {
  union { float f; unsigned int i; } v; v.f = f;
  unsigned int r = v.i + 0x7FFFu + ((v.i >> 16) & 1u);
  return (ushort_t)(r >> 16);
}
__device__ __forceinline__ float sigmoidf_(float x) { return 1.f / (1.f + __expf(-x)); }
__device__ __forceinline__ float tanhf_(float x) {
  float e = __expf(2.f * x); return 1.f - 2.f / (e + 1.f);
}

// Group barrier among 32 WGs (round-2 semantics + split counter/go lines).
// __syncthreads drains vmcnt(0) => all this WG's bypass-stores are at the LLC
// before thread 0 posts. Last arriver (fetch_add returns target-1) publishes
// the release word; everyone else polls the 1-writer go line.
__device__ __forceinline__ void group_barrier(unsigned* cnt, unsigned* go,
                                              unsigned target) {
  __syncthreads();
  if (threadIdx.x == 0) {
    unsigned old = __hip_atomic_fetch_add(cnt, 1u, __ATOMIC_RELAXED,
                                          __HIP_MEMORY_SCOPE_AGENT);
    if (old + 1u == target) {
      AT_STORE(go, target);
    } else {
      while (AT_LOAD(go) < target) { }
    }
  }
  __syncthreads();
}

__device__ __forceinline__ short8 pack_bf16_8(const float* p) {
  float4 a = *(const float4*)p;
  float4 b = *(const float4*)(p + 4);
  short8 f;
  f[0] = (short)f2bf(a.x); f[1] = (short)f2bf(a.y);
  f[2] = (short)f2bf(a.z); f[3] = (short)f2bf(a.w);
  f[4] = (short)f2bf(b.x); f[5] = (short)f2bf(b.y);
  f[6] = (short)f2bf(b.z); f[7] = (short)f2bf(b.w);
  return f;
}

// counters layout (uints): [g*32] barrier counter for group g (g<8);
// [256 + g*32] go word for group g. Lines are 128B apart everywhere.
__global__ void __launch_bounds__(256, 1) ghost_gru_persistent(
    const float* __restrict__ x, const float* __restrict__ hidden,
    const float* __restrict__ Wg, const float* __restrict__ Wc,
    const float* __restrict__ Wgh, const float* __restrict__ bg,
    const float* __restrict__ bc, const float* __restrict__ bgh,
    float* __restrict__ out, unsigned int* __restrict__ hbuf_u,
    unsigned int* __restrict__ rs_u, float* __restrict__ ubuf,
    unsigned int* __restrict__ counters)
{
  const int wgid = blockIdx.x;
  const int g    = wgid & 7;      // group (XCD-affine heuristic; perf only)
  const int memb = wgid >> 3;     // member 0..31 within group
  const int b0   = g * 16;        // batch base
  const int tid  = threadIdx.x;
  const int wv   = tid >> 6;      // wave 0..3
  const int lane = tid & 63;
  const int lq   = lane >> 4;     // quad 0..3
  const int ln   = lane & 15;
  unsigned* cnt = counters + g * 32;
  unsigned* go  = counters + 256 + g * 32;

  // A-staging (bf16): [16 batches][ x(0..255) | ghost(256..767) | newh(768..1279) | rstate(1280..1791) | pad ]
  // Row stride 1800 ushorts = 3600 B (16B-aligned rows given align(16) base).
  __shared__ __align__(16) ushort_t Abuf[16][1800];

  // VGPR-resident weight fragments: B-frag lane (n + 16q) holds W[n][kc*32 + 8q .. +7]
  short8 wfrag[40];
  int ncol0;
  float biasv;
  if (wv == 0 || wv == 1) {                    // gate: 32 cols per WG, 16 per wave
    ncol0 = memb * 32 + wv * 16;
    const float* wp = Wg + (size_t)(ncol0 + ln) * KGATE + lq * 8;
    #pragma unroll
    for (int kc = 0; kc < 40; ++kc) wfrag[kc] = pack_bf16_8(wp + kc * 32);
    biasv = bg[ncol0 + ln];
  } else if (wv == 2) {                        // candidate: 16 cols
    ncol0 = memb * 16;
    const float* wp = Wc + (size_t)(ncol0 + ln) * KGATE + lq * 8;
    #pragma unroll
    for (int kc = 0; kc < 40; ++kc) wfrag[kc] = pack_bf16_8(wp + kc * 32);
    biasv = bc[ncol0 + ln];
  } else {                                     // ghost: 16 cols, K=512
    ncol0 = memb * 16;
    const float* wp = Wgh + (size_t)(ncol0 + ln) * 512 + lq * 8;
    #pragma unroll
    for (int kc = 0; kc < 16; ++kc) wfrag[kc] = pack_bf16_8(wp + kc * 32);
    biasv = bgh[ncol0 + ln];
  }

  // fp32 master copy of new_h state, held by cand wave across all steps.
  float hreg[4];
  if (wv == 2) {
    #pragma unroll
    for (int r = 0; r < 4; ++r)
      hreg[r] = hidden[(size_t)(b0 + lq * 4 + r) * NH + 512 + ncol0 + ln];
  }

  const ull_t* hbuf64 = (const ull_t*)hbuf_u;
  const ull_t* rs64   = (const ull_t*)rs_u;

  // Pre-stage newh(h0) into Abuf[.][768..1280). It persists across steps
  // (refreshed by the post-barrier-2 staging), never re-staged at loop top.
  {
    ull_t nv[8];
    #pragma unroll
    for (int k = 0; k < 8; ++k) {
      int j = tid + k * 256;               // 0..2047 over 16 rows x 128 ull
      nv[k] = AT_LOAD(&hbuf64[(size_t)(b0 + (j >> 7)) * 256 + 128 + (j & 127)]);
    }
    #pragma unroll
    for (int k = 0; k < 8; ++k) {
      int j = tid + k * 256;
      *(ull_t*)&Abuf[j >> 7][768 + 4 * (j & 127)] = nv[k];
    }
  }

  // Prefetch x_0 into registers.
  float4 xv[4];
  #pragma unroll
  for (int k = 0; k < 4; ++k) {
    int i = tid + k * 256;
    xv[k] = *(const float4*)&x[((size_t)(b0 + (i >> 6)) * NT + 0) * NF + (i & 63) * 4];
  }

  #pragma unroll 1
  for (int t = 0; t < NT; ++t) {
    const int cur = t & 1, nxt = cur ^ 1;
    const ull_t* hsrc64 = hbuf64 + (size_t)cur * NB * 256;
    unsigned*    hdst   = hbuf_u + (size_t)nxt * NB * 512;
    const ull_t* hdst64 = hbuf64 + (size_t)nxt * NB * 256;

    // ---- loop top: x_t from prefetch regs -> LDS; stage ghost (8B loads) ----
    {
      ull_t gv[8];
      #pragma unroll
      for (int k = 0; k < 8; ++k) {
        int j = tid + k * 256;
        gv[k] = AT_LOAD(&hsrc64[(size_t)(b0 + (j >> 7)) * 256 + (j & 127)]);
      }
      #pragma unroll
      for (int k = 0; k < 4; ++k) {
        int i = tid + k * 256;
        int row = i >> 6, c4 = (i & 63) * 4;
        ushort4 u4 = make_ushort4(f2bf(xv[k].x), f2bf(xv[k].y),
                                  f2bf(xv[k].z), f2bf(xv[k].w));
        *(ushort4*)&Abuf[row][c4] = u4;
      }
      #pragma unroll
      for (int k = 0; k < 8; ++k) {
        int j = tid + k * 256;
        *(ull_t*)&Abuf[j >> 7][256 + 4 * (j & 127)] = gv[k];
      }
    }
    __syncthreads();

    // issue next-step x prefetch (completes during this step's phases)
    {
      const int tn = (t + 1 < NT) ? t + 1 : t;
      #pragma unroll
      for (int k = 0; k < 4; ++k) {
        int i = tid + k * 256;
        xv[k] = *(const float4*)&x[((size_t)(b0 + (i >> 6)) * NT + tn) * NF + (i & 63) * 4];
      }
    }

    // ---- phase 1: gate = sigmoid([x,ghost,newh] @ Wg^T + bg) ----
    if (wv < 2) {
      f32x4 acc0 = {0.f, 0.f, 0.f, 0.f}, acc1 = {0.f, 0.f, 0.f, 0.f};
      #pragma unroll
      for (int kc = 0; kc < 40; kc += 2) {
        short8 a0 = *(const short8*)&Abuf[ln][kc * 32 + lq * 8];
        acc0 = __builtin_amdgcn_mfma_f32_16x16x32_bf16(a0, wfrag[kc], acc0, 0, 0, 0);
        short8 a1 = *(const short8*)&Abuf[ln][(kc + 1) * 32 + lq * 8];
        acc1 = __builtin_amdgcn_mfma_f32_16x16x32_bf16(a1, wfrag[kc + 1], acc1, 0, 0, 0);
      }
      const int n = ncol0 + ln;
      if (ncol0 < 512) {  // r-gate -> rstate = r * h_old[newh part]
        #pragma unroll
        for (int r = 0; r < 4; ++r) {
          int row = lq * 4 + r;
          float s = sigmoidf_(acc0[r] + acc1[r] + biasv);
          float hold = bf2f(Abuf[row][768 + n]);
          unsigned hv = (unsigned)f2bf(s * hold);
          unsigned pv = (unsigned)__shfl_xor((int)hv, 1);
          if (!(ln & 1))
            AT_STORE(&rs_u[(size_t)(b0 + row) * 256 + (n >> 1)], hv | (pv << 16));
        }
      } else {            // u-gate (fp32 for state update)
        #pragma unroll
        for (int r = 0; r < 4; ++r) {
          int row = lq * 4 + r;
          float s = sigmoidf_(acc0[r] + acc1[r] + biasv);
          AT_STORE(&ubuf[(size_t)(b0 + row) * 512 + (n - 512)], s);
        }
      }
    }
    group_barrier(cnt, go, 32u * (3u * (unsigned)t + 1u));

    // ---- phase 2: c = tanh([x,ghost,rstate] @ Wc^T + bc); new_h = u*h+(1-u)*c
    // Waves 0/1 stage rstate while wave 2 prefetches u and runs its 24
    // x+ghost MFMAs — the rstate round trip hides under compute.
    float uval[4];
    f32x4 acc0c = {0.f, 0.f, 0.f, 0.f}, acc1c = {0.f, 0.f, 0.f, 0.f};
    if (wv == 2) {
      #pragma unroll
      for (int r = 0; r < 4; ++r)
        uval[r] = AT_LOAD(&ubuf[(size_t)(b0 + lq * 4 + r) * 512 + ncol0 + ln]);
      #pragma unroll
      for (int kc = 0; kc < 24; kc += 2) {
        short8 a0 = *(const short8*)&Abuf[ln][kc * 32 + lq * 8];
        acc0c = __builtin_amdgcn_mfma_f32_16x16x32_bf16(a0, wfrag[kc], acc0c, 0, 0, 0);
        short8 a1 = *(const short8*)&Abuf[ln][(kc + 1) * 32 + lq * 8];
        acc1c = __builtin_amdgcn_mfma_f32_16x16x32_bf16(a1, wfrag[kc + 1], acc1c, 0, 0, 0);
      }
    } else if (wv < 2) {
      ull_t rv[16];
      #pragma unroll
      for (int k = 0; k < 16; ++k) {
        int j = tid + k * 128;               // tid<128 here; 0..2047
        rv[k] = AT_LOAD(&rs64[(size_t)(b0 + (j >> 7)) * 128 + (j & 127)]);
      }
      #pragma unroll
      for (int k = 0; k < 16; ++k) {
        int j = tid + k * 128;
        *(ull_t*)&Abuf[j >> 7][1280 + 4 * (j & 127)] = rv[k];
      }
    }
    __syncthreads();
    if (wv == 2) {
      #pragma unroll
      for (int kc = 24; kc < 40; kc += 2) {
        short8 a0 = *(const short8*)&Abuf[ln][1280 + (kc - 24) * 32 + lq * 8];
        acc0c = __builtin_amdgcn_mfma_f32_16x16x32_bf16(a0, wfrag[kc], acc0c, 0, 0, 0);
        short8 a1 = *(const short8*)&Abuf[ln][1280 + (kc - 23) * 32 + lq * 8];
        acc1c = __builtin_amdgcn_mfma_f32_16x16x32_bf16(a1, wfrag[kc + 1], acc1c, 0, 0, 0);
      }
      const int n = ncol0 + ln;
      #pragma unroll
      for (int r = 0; r < 4; ++r) {
        int row = lq * 4 + r;
        int b = b0 + row;
        float cv = tanhf_(acc0c[r] + acc1c[r] + biasv);
        float u = uval[r];
        float hnew = u * hreg[r] + (1.f - u) * cv;
        hreg[r] = hnew;
        out[((size_t)b * NT + t) * NH + 512 + n] = hnew;
        unsigned hv = (unsigned)f2bf(hnew);
        unsigned pv = (unsigned)__shfl_xor((int)hv, 1);
        if (!(ln & 1))
          AT_STORE(&hdst[(size_t)b * 512 + 256 + (n >> 1)], hv | (pv << 16));
        if (t == NT - 1) out[(size_t)NB * NT * NH + (size_t)b * NH + 512 + n] = hnew;
      }
    }
    group_barrier(cnt, go, 32u * (3u * (unsigned)t + 2u));

    // ---- stage fresh new_h (8B loads) into Abuf[.][768..1280) ----
    // (also serves next step's phase 1: newh persists in LDS)
    {
      ull_t nv[8];
      #pragma unroll
      for (int k = 0; k < 8; ++k) {
        int j = tid + k * 256;
        nv[k] = AT_LOAD(&hdst64[(size_t)(b0 + (j >> 7)) * 256 + 128 + (j & 127)]);
      }
      #pragma unroll
      for (int k = 0; k < 8; ++k) {
        int j = tid + k * 256;
        *(ull_t*)&Abuf[j >> 7][768 + 4 * (j & 127)] = nv[k];
      }
    }
    __syncthreads();

    // ---- phase 3: ghost = tanh(new_h @ Wgh^T + bgh) ----
    if (wv == 3) {
      f32x4 acc = {0.f, 0.f, 0.f, 0.f};
      #pragma unroll
      for (int kc = 0; kc < 16; ++kc) {
        short8 a = *(const short8*)&Abuf[ln][768 + kc * 32 + lq * 8];
        acc = __builtin_amdgcn_mfma_f32_16x16x32_bf16(a, wfrag[kc], acc, 0, 0, 0);
      }
      const int n = ncol0 + ln;
      #pragma unroll
      for (int r = 0; r < 4; ++r) {
        int row = lq * 4 + r;
        int b = b0 + row;
        float gv = tanhf_(acc[r] + biasv);
        out[((size_t)b * NT + t) * NH + n] = gv;
        unsigned hv = (unsigned)f2bf(gv);
        unsigned pv = (unsigned)__shfl_xor((int)hv, 1);
        if (!(ln & 1))
          AT_STORE(&hdst[(size_t)b * 512 + (n >> 1)], hv | (pv << 16));
        if (t == NT - 1) out[(size_t)NB * NT * NH + (size_t)b * NH + n] = gv;
      }
    }
    group_barrier(cnt, go, 32u * (3u * (unsigned)t + 3u));
  }
}

__global__ void init_kernel(const float* __restrict__ hidden,
                            unsigned int* __restrict__ hbuf_u,
                            unsigned int* __restrict__ counters) {
  int i = blockIdx.x * blockDim.x + threadIdx.x;
  if (i < NB * 512) {  // pack h0 into bf16 pairs; hbuf[0] = h0
    unsigned lo = (unsigned)f2bf(hidden[2 * i]);
    unsigned hi = (unsigned)f2bf(hidden[2 * i + 1]);
    hbuf_u[i] = lo | (hi << 16);
  }
  if (i < 512) counters[i] = 0;  // barrier counters [0..255] + go words [256..511]
}

extern "C" void kernel_launch(void* const* d_in, const int* in_sizes, int n_in,
                              void* d_out, int out_size, void* d_ws, size_t ws_size,
                              hipStream_t stream) {
  (void)in_sizes; (void)n_in; (void)out_size; (void)ws_size;
  const float* x      = (const float*)d_in[0];
  const float* hidden = (const float*)d_in[1];
  const float* Wg     = (const float*)d_in[2];
  const float* Wc     = (const float*)d_in[3];
  const float* Wgh    = (const float*)d_in[4];
  const float* bg     = (const float*)d_in[5];
  const float* bc     = (const float*)d_in[6];
  const float* bgh    = (const float*)d_in[7];
  float* out = (float*)d_out;

  char* ws = (char*)d_ws;
  unsigned int* hbuf_u   = (unsigned int*)(ws);         // 2 * 128*512 uints = 512 KB
  unsigned int* rs_u     = (unsigned int*)(ws + 524288);// 128*256 uints = 128 KB
  float*        ubuf     = (float*)(ws + 655360);       // 128*512 f32  = 256 KB
  unsigned int* counters = (unsigned int*)(ws + 917504);// 512 uints = 2 KB

  init_kernel<<<dim3(256), dim3(256), 0, stream>>>(hidden, hbuf_u, counters);
  ghost_gru_persistent<<<dim3(256), dim3(256), 0, stream>>>(
      x, hidden, Wg, Wc, Wgh, bg, bc, bgh, out, hbuf_u, rs_u, ubuf, counters);
}

// Round 4
// 4059.783 us; speedup vs baseline: 1.3834x; 1.1015x over previous
//
#include <hip/hip_runtime.h>

// GhostGRU persistent-RNN kernel for MI355X (gfx950), round 6.
// Base: round-5 (4472 us, passed). Changes (pure builtins, no inline asm):
//  1. Flag-array barrier: per-WG flag slots (single writer each), posted with
//     a relaxed agent store after __syncthreads (vmcnt drain). Consumers do a
//     wave-parallel poll: lane i loads flag[i&31] (one coalesced vector load
//     polls all 32 flags), exit when __all(f >= target). Removes the central
//     fetch_add hop, go-word publication hop, and the trailing __syncthreads
//     of the old barrier (~1.5 LLC round-trips x 3 barriers per step).
//  2. u-localization: gate columns remapped so wave 0 of WG m computes r-cols
//     [16m,16m+16) and wave 1 computes u-cols [512+16m,+16). The u values a WG
//     produces are exactly what its own cand wave consumes -> u passes via LDS
//     (1 KB region), ubuf and its LLC traffic are deleted.
// Kept from round 5: newh persists in LDS across steps; rstate staged by idle
// waves 0/1 under cand's 24 x+ghost MFMAs; x_t prefetched one step ahead;
// 8-byte staging loads; agent-scope (LLC) relaxed atomics for all cross-WG
// data (proven protocol).

typedef unsigned short ushort_t;
typedef unsigned long long ull_t;
typedef __attribute__((ext_vector_type(8))) short short8;   // 8 x bf16 (4 VGPRs)
typedef __attribute__((ext_vector_type(4))) float f32x4;

#define NB 128
#define NT 512
#define NF 256
#define NH 1024
#define KGATE 1280

#define AT_LOAD(p)     __hip_atomic_load((p), __ATOMIC_RELAXED, __HIP_MEMORY_SCOPE_AGENT)
#define AT_STORE(p,v)  __hip_atomic_store((p), (v), __ATOMIC_RELAXED, __HIP_MEMORY_SCOPE_AGENT)

__device__ __forceinline__ float bf2f(ushort_t u) {
  union { unsigned int i; float f; } v; v.i = ((unsigned int)u) << 16; return v.f;
}
__device__ __forceinline__ ushort_t f2bf(float f) {
  union { float f; unsigned int i; } v; v.f = f;
  unsigned int r = v.i + 0x7FFFu + ((v.i >> 16) & 1u);
  return (ushort_t)(r >> 16);
}
__device__ __forceinline__ float sigmoidf_(float x) { return 1.f / (1.f + __expf(-x)); }
__device__ __forceinline__ float tanhf_(float x) {
  float e = __expf(2.f * x); return 1.f - 2.f / (e + 1.f);
}

// Post this WG's arrival at phase value `val`. __syncthreads drains vmcnt(0)
// for every wave first => all this WG's data stores are at the LLC before the
// single-writer flag slot is updated.
__device__ __forceinline__ void post_flag(unsigned* flags, int memb, unsigned val) {
  __syncthreads();
  if (threadIdx.x == 0) AT_STORE(&flags[memb], val);
}

// Wave-parallel wait: every thread polls flag[lane&31]; one coalesced load
// per iteration covers all 32 flags. Flags are monotonic, so exit is stable.
__device__ __forceinline__ void wait_flags(const unsigned* flags, unsigned tgt) {
  const int sl = (int)(threadIdx.x & 31u);
  for (;;) {
    unsigned f = AT_LOAD(&flags[sl]);
    if (__all((int)(f >= tgt))) break;
    __builtin_amdgcn_s_sleep(1);
  }
  __builtin_amdgcn_sched_barrier(0);   // keep staged loads below the wait
}

__device__ __forceinline__ short8 pack_bf16_8(const float* p) {
  float4 a = *(const float4*)p;
  float4 b = *(const float4*)(p + 4);
  short8 f;
  f[0] = (short)f2bf(a.x); f[1] = (short)f2bf(a.y);
  f[2] = (short)f2bf(a.z); f[3] = (short)f2bf(a.w);
  f[4] = (short)f2bf(b.x); f[5] = (short)f2bf(b.y);
  f[6] = (short)f2bf(b.z); f[7] = (short)f2bf(b.w);
  return f;
}

// counters layout (uints): group g's 32 flag slots at [g*64 .. g*64+32).
__global__ void __launch_bounds__(256, 1) ghost_gru_persistent(
    const float* __restrict__ x, const float* __restrict__ hidden,
    const float* __restrict__ Wg, const float* __restrict__ Wc,
    const float* __restrict__ Wgh, const float* __restrict__ bg,
    const float* __restrict__ bc, const float* __restrict__ bgh,
    float* __restrict__ out, unsigned int* __restrict__ hbuf_u,
    unsigned int* __restrict__ rs_u, unsigned int* __restrict__ counters)
{
  const int wgid = blockIdx.x;
  const int g    = wgid & 7;      // group (XCD-affine heuristic; perf only)
  const int memb = wgid >> 3;     // member 0..31 within group
  const int b0   = g * 16;        // batch base
  const int tid  = threadIdx.x;
  const int wv   = tid >> 6;      // wave 0..3
  const int lane = tid & 63;
  const int lq   = lane >> 4;     // quad 0..3
  const int ln   = lane & 15;
  unsigned* flags = counters + g * 64;

  // A-staging (bf16): [16 batches][ x(0..255) | ghost(256..767) | newh(768..1279)
  //   | rstate(1280..1791) | u-f32(1792..1823) | pad ]
  // Row stride 1832 ushorts = 3664 B (16B-aligned rows given align(16) base).
  __shared__ __align__(16) ushort_t Abuf[16][1832];

  // VGPR-resident weight fragments: B-frag lane (n + 16q) holds W[n][kc*32 + 8q .. +7]
  // Gate mapping (u-localization): wave 0 -> r-cols [16*memb, +16);
  // wave 1 -> u-cols [512 + 16*memb, +16) — same memb as this WG's cand cols.
  short8 wfrag[40];
  int ncol0;
  float biasv;
  if (wv == 0) {                               // r-gate: 16 cols
    ncol0 = memb * 16;
    const float* wp = Wg + (size_t)(ncol0 + ln) * KGATE + lq * 8;
    #pragma unroll
    for (int kc = 0; kc < 40; ++kc) wfrag[kc] = pack_bf16_8(wp + kc * 32);
    biasv = bg[ncol0 + ln];
  } else if (wv == 1) {                        // u-gate: 16 cols
    ncol0 = 512 + memb * 16;
    const float* wp = Wg + (size_t)(ncol0 + ln) * KGATE + lq * 8;
    #pragma unroll
    for (int kc = 0; kc < 40; ++kc) wfrag[kc] = pack_bf16_8(wp + kc * 32);
    biasv = bg[ncol0 + ln];
  } else if (wv == 2) {                        // candidate: 16 cols
    ncol0 = memb * 16;
    const float* wp = Wc + (size_t)(ncol0 + ln) * KGATE + lq * 8;
    #pragma unroll
    for (int kc = 0; kc < 40; ++kc) wfrag[kc] = pack_bf16_8(wp + kc * 32);
    biasv = bc[ncol0 + ln];
  } else {                                     // ghost: 16 cols, K=512
    ncol0 = memb * 16;
    const float* wp = Wgh + (size_t)(ncol0 + ln) * 512 + lq * 8;
    #pragma unroll
    for (int kc = 0; kc < 16; ++kc) wfrag[kc] = pack_bf16_8(wp + kc * 32);
    biasv = bgh[ncol0 + ln];
  }

  // fp32 master copy of new_h state, held by cand wave across all steps.
  float hreg[4];
  if (wv == 2) {
    #pragma unroll
    for (int r = 0; r < 4; ++r)
      hreg[r] = hidden[(size_t)(b0 + lq * 4 + r) * NH + 512 + ncol0 + ln];
  }

  const ull_t* hbuf64 = (const ull_t*)hbuf_u;
  const ull_t* rs64   = (const ull_t*)rs_u;

  // Pre-stage newh(h0) into Abuf[.][768..1280). It persists across steps
  // (refreshed by the post-phase-2 staging), never re-staged at loop top.
  {
    ull_t nv[8];
    #pragma unroll
    for (int k = 0; k < 8; ++k) {
      int j = tid + k * 256;               // 0..2047 over 16 rows x 128 ull
      nv[k] = AT_LOAD(&hbuf64[(size_t)(b0 + (j >> 7)) * 256 + 128 + (j & 127)]);
    }
    #pragma unroll
    for (int k = 0; k < 8; ++k) {
      int j = tid + k * 256;
      *(ull_t*)&Abuf[j >> 7][768 + 4 * (j & 127)] = nv[k];
    }
  }

  // Prefetch x_0 into registers.
  float4 xv[4];
  #pragma unroll
  for (int k = 0; k < 4; ++k) {
    int i = tid + k * 256;
    xv[k] = *(const float4*)&x[((size_t)(b0 + (i >> 6)) * NT + 0) * NF + (i & 63) * 4];
  }

  #pragma unroll 1
  for (int t = 0; t < NT; ++t) {
    const int cur = t & 1, nxt = cur ^ 1;
    const ull_t* hsrc64 = hbuf64 + (size_t)cur * NB * 256;
    unsigned*    hdst   = hbuf_u + (size_t)nxt * NB * 512;
    const ull_t* hdst64 = hbuf64 + (size_t)nxt * NB * 256;

    // ---- loop top: x_t from prefetch regs -> LDS; stage ghost (8B loads) ----
    {
      ull_t gv[8];
      #pragma unroll
      for (int k = 0; k < 8; ++k) {
        int j = tid + k * 256;
        gv[k] = AT_LOAD(&hsrc64[(size_t)(b0 + (j >> 7)) * 256 + (j & 127)]);
      }
      #pragma unroll
      for (int k = 0; k < 4; ++k) {
        int i = tid + k * 256;
        int row = i >> 6, c4 = (i & 63) * 4;
        ushort4 u4 = make_ushort4(f2bf(xv[k].x), f2bf(xv[k].y),
                                  f2bf(xv[k].z), f2bf(xv[k].w));
        *(ushort4*)&Abuf[row][c4] = u4;
      }
      #pragma unroll
      for (int k = 0; k < 8; ++k) {
        int j = tid + k * 256;
        *(ull_t*)&Abuf[j >> 7][256 + 4 * (j & 127)] = gv[k];
      }
    }
    __syncthreads();

    // issue next-step x prefetch (completes during this step's phases)
    {
      const int tn = (t + 1 < NT) ? t + 1 : t;
      #pragma unroll
      for (int k = 0; k < 4; ++k) {
        int i = tid + k * 256;
        xv[k] = *(const float4*)&x[((size_t)(b0 + (i >> 6)) * NT + tn) * NF + (i & 63) * 4];
      }
    }

    // ---- phase 1: gate = sigmoid([x,ghost,newh] @ Wg^T + bg) ----
    if (wv < 2) {
      f32x4 acc0 = {0.f, 0.f, 0.f, 0.f}, acc1 = {0.f, 0.f, 0.f, 0.f};
      #pragma unroll
      for (int kc = 0; kc < 40; kc += 2) {
        short8 a0 = *(const short8*)&Abuf[ln][kc * 32 + lq * 8];
        acc0 = __builtin_amdgcn_mfma_f32_16x16x32_bf16(a0, wfrag[kc], acc0, 0, 0, 0);
        short8 a1 = *(const short8*)&Abuf[ln][(kc + 1) * 32 + lq * 8];
        acc1 = __builtin_amdgcn_mfma_f32_16x16x32_bf16(a1, wfrag[kc + 1], acc1, 0, 0, 0);
      }
      const int n = ncol0 + ln;
      if (wv == 0) {      // r-gate -> rstate = r * h_old[newh part] (cross-WG)
        #pragma unroll
        for (int r = 0; r < 4; ++r) {
          int row = lq * 4 + r;
          float s = sigmoidf_(acc0[r] + acc1[r] + biasv);
          float hold = bf2f(Abuf[row][768 + n]);
          unsigned hv = (unsigned)f2bf(s * hold);
          unsigned pv = (unsigned)__shfl_xor((int)hv, 1);
          if (!(ln & 1))
            AT_STORE(&rs_u[(size_t)(b0 + row) * 256 + (n >> 1)], hv | (pv << 16));
        }
      } else {            // u-gate -> LDS only (consumed by this WG's cand wave)
        #pragma unroll
        for (int r = 0; r < 4; ++r) {
          int row = lq * 4 + r;
          float s = sigmoidf_(acc0[r] + acc1[r] + biasv);
          ((float*)&Abuf[row][1792])[ln] = s;
        }
      }
    }
    post_flag(flags, memb, 3u * (unsigned)t + 1u);
    wait_flags(flags, 3u * (unsigned)t + 1u);

    // ---- phase 2: c = tanh([x,ghost,rstate] @ Wc^T + bc); new_h = u*h+(1-u)*c
    // Waves 0/1 stage rstate while wave 2 reads u from LDS and runs its 24
    // x+ghost MFMAs — the rstate round trip hides under compute.
    float uval[4];
    f32x4 acc0c = {0.f, 0.f, 0.f, 0.f}, acc1c = {0.f, 0.f, 0.f, 0.f};
    if (wv == 2) {
      #pragma unroll
      for (int r = 0; r < 4; ++r)
        uval[r] = ((const float*)&Abuf[lq * 4 + r][1792])[ln];
      #pragma unroll
      for (int kc = 0; kc < 24; kc += 2) {
        short8 a0 = *(const short8*)&Abuf[ln][kc * 32 + lq * 8];
        acc0c = __builtin_amdgcn_mfma_f32_16x16x32_bf16(a0, wfrag[kc], acc0c, 0, 0, 0);
        short8 a1 = *(const short8*)&Abuf[ln][(kc + 1) * 32 + lq * 8];
        acc1c = __builtin_amdgcn_mfma_f32_16x16x32_bf16(a1, wfrag[kc + 1], acc1c, 0, 0, 0);
      }
    } else if (wv < 2) {
      ull_t rv[16];
      #pragma unroll
      for (int k = 0; k < 16; ++k) {
        int j = tid + k * 128;               // tid<128 here; 0..2047
        rv[k] = AT_LOAD(&rs64[(size_t)(b0 + (j >> 7)) * 128 + (j & 127)]);
      }
      #pragma unroll
      for (int k = 0; k < 16; ++k) {
        int j = tid + k * 128;
        *(ull_t*)&Abuf[j >> 7][1280 + 4 * (j & 127)] = rv[k];
      }
    }
    __syncthreads();
    if (wv == 2) {
      #pragma unroll
      for (int kc = 24; kc < 40; kc += 2) {
        short8 a0 = *(const short8*)&Abuf[ln][1280 + (kc - 24) * 32 + lq * 8];
        acc0c = __builtin_amdgcn_mfma_f32_16x16x32_bf16(a0, wfrag[kc], acc0c, 0, 0, 0);
        short8 a1 = *(const short8*)&Abuf[ln][1280 + (kc - 23) * 32 + lq * 8];
        acc1c = __builtin_amdgcn_mfma_f32_16x16x32_bf16(a1, wfrag[kc + 1], acc1c, 0, 0, 0);
      }
      const int n = ncol0 + ln;
      #pragma unroll
      for (int r = 0; r < 4; ++r) {
        int row = lq * 4 + r;
        int b = b0 + row;
        float cv = tanhf_(acc0c[r] + acc1c[r] + biasv);
        float u = uval[r];
        float hnew = u * hreg[r] + (1.f - u) * cv;
        hreg[r] = hnew;
        out[((size_t)b * NT + t) * NH + 512 + n] = hnew;
        unsigned hv = (unsigned)f2bf(hnew);
        unsigned pv = (unsigned)__shfl_xor((int)hv, 1);
        if (!(ln & 1))
          AT_STORE(&hdst[(size_t)b * 512 + 256 + (n >> 1)], hv | (pv << 16));
        if (t == NT - 1) out[(size_t)NB * NT * NH + (size_t)b * NH + 512 + n] = hnew;
      }
    }
    post_flag(flags, memb, 3u * (unsigned)t + 2u);
    wait_flags(flags, 3u * (unsigned)t + 2u);

    // ---- stage fresh new_h (8B loads) into Abuf[.][768..1280) ----
    // (also serves next step's phase 1: newh persists in LDS)
    {
      ull_t nv[8];
      #pragma unroll
      for (int k = 0; k < 8; ++k) {
        int j = tid + k * 256;
        nv[k] = AT_LOAD(&hdst64[(size_t)(b0 + (j >> 7)) * 256 + 128 + (j & 127)]);
      }
      #pragma unroll
      for (int k = 0; k < 8; ++k) {
        int j = tid + k * 256;
        *(ull_t*)&Abuf[j >> 7][768 + 4 * (j & 127)] = nv[k];
      }
    }
    __syncthreads();

    // ---- phase 3: ghost = tanh(new_h @ Wgh^T + bgh) ----
    if (wv == 3) {
      f32x4 acc = {0.f, 0.f, 0.f, 0.f};
      #pragma unroll
      for (int kc = 0; kc < 16; ++kc) {
        short8 a = *(const short8*)&Abuf[ln][768 + kc * 32 + lq * 8];
        acc = __builtin_amdgcn_mfma_f32_16x16x32_bf16(a, wfrag[kc], acc, 0, 0, 0);
      }
      const int n = ncol0 + ln;
      #pragma unroll
      for (int r = 0; r < 4; ++r) {
        int row = lq * 4 + r;
        int b = b0 + row;
        float gv = tanhf_(acc[r] + biasv);
        out[((size_t)b * NT + t) * NH + n] = gv;
        unsigned hv = (unsigned)f2bf(gv);
        unsigned pv = (unsigned)__shfl_xor((int)hv, 1);
        if (!(ln & 1))
          AT_STORE(&hdst[(size_t)b * 512 + (n >> 1)], hv | (pv << 16));
        if (t == NT - 1) out[(size_t)NB * NT * NH + (size_t)b * NH + n] = gv;
      }
    }
    post_flag(flags, memb, 3u * (unsigned)t + 3u);
    wait_flags(flags, 3u * (unsigned)t + 3u);
  }
}

__global__ void init_kernel(const float* __restrict__ hidden,
                            unsigned int* __restrict__ hbuf_u,
                            unsigned int* __restrict__ counters) {
  int i = blockIdx.x * blockDim.x + threadIdx.x;
  if (i < NB * 512) {  // pack h0 into bf16 pairs; hbuf[0] = h0
    unsigned lo = (unsigned)f2bf(hidden[2 * i]);
    unsigned hi = (unsigned)f2bf(hidden[2 * i + 1]);
    hbuf_u[i] = lo | (hi << 16);
  }
  if (i < 512) counters[i] = 0;  // 8 groups x 64-uint flag blocks
}

extern "C" void kernel_launch(void* const* d_in, const int* in_sizes, int n_in,
                              void* d_out, int out_size, void* d_ws, size_t ws_size,
                              hipStream_t stream) {
  (void)in_sizes; (void)n_in; (void)out_size; (void)ws_size;
  const float* x      = (const float*)d_in[0];
  const float* hidden = (const float*)d_in[1];
  const float* Wg     = (const float*)d_in[2];
  const float* Wc     = (const float*)d_in[3];
  const float* Wgh    = (const float*)d_in[4];
  const float* bg     = (const float*)d_in[5];
  const float* bc     = (const float*)d_in[6];
  const float* bgh    = (const float*)d_in[7];
  float* out = (float*)d_out;

  char* ws = (char*)d_ws;
  unsigned int* hbuf_u   = (unsigned int*)(ws);         // 2 * 128*512 uints = 512 KB
  unsigned int* rs_u     = (unsigned int*)(ws + 524288);// 128*256 uints = 128 KB
  unsigned int* counters = (unsigned int*)(ws + 655360);// 512 uints = 2 KB

  init_kernel<<<dim3(256), dim3(256), 0, stream>>>(hidden, hbuf_u, counters);
  ghost_gru_persistent<<<dim3(256), dim3(256), 0, stream>>>(
      x, hidden, Wg, Wc, Wgh, bg, bc, bgh, out, hbuf_u, rs_u, counters);
}